// Round 1
// baseline (125.079 us; speedup 1.0000x reference)
//
#include <hip/hip_runtime.h>

// Conv2d 3x3 s1 p1, N=16 C=64 H=W=112 F=64, fp32 in/out, bf16 MFMA implicit GEMM.
// R6: W-split blocks (64+48 cols) -> LDS 33.8 KB -> 4 blocks/CU resident (was 2).
// LDS layout [dy][ch-octet][wcol][8ch] (16B pitch/wcol): bank = (8*oct+4*wcol)&31,
// conflict-free for ds_read_b128 A-frags and b128 staging writes (no XOR needed).
// Direct float4 epilogue from acc (bias in-register): 1 barrier total, no LDS bounce.

typedef __attribute__((ext_vector_type(8))) short bf16x8;
typedef __attribute__((ext_vector_type(4))) float f32x4;

#define CIN 64
#define COUT 64
#define HH 112
#define WW 112
#define ROWS 2            // output rows per block
#define DYS  4            // staged input rows (ROWS + 2)
#define WCMAX 66          // staged wcols (left block: 1 pad + 64 + 1 halo)
#define PLANE (8 * WCMAX * 8)          // shorts per dy plane = 4224 (8448 B)
#define LDS_SHORTS (DYS * PLANE)       // 16896 shorts = 33792 B -> 4 blocks/CU

__device__ __forceinline__ int ladr(int dy, int oct, int w) {
    // bf16 [dy][oct][wcol][8ch]; addr in shorts. Bank of 16B unit: (8*oct+4*w)&31.
    return ((dy * 8 + oct) * WCMAX + w) * 8;
}

__device__ __forceinline__ unsigned short f2bf(float f) {
    unsigned u = __builtin_bit_cast(unsigned, f);
    u += 0x7FFFu + ((u >> 16) & 1u);   // round-to-nearest-even
    return (unsigned short)(u >> 16);
}

#if __has_builtin(__builtin_amdgcn_cvt_pk_bf16_f32)
__device__ __forceinline__ unsigned pk2bf(float a, float b) {
    typedef __attribute__((ext_vector_type(2))) __bf16 bf16x2;
    bf16x2 r = __builtin_amdgcn_cvt_pk_bf16_f32(a, b);
    return __builtin_bit_cast(unsigned, r);
}
#else
__device__ __forceinline__ unsigned pk2bf(float a, float b) {
    return (unsigned)f2bf(a) | ((unsigned)f2bf(b) << 16);
}
#endif

// ---- one-time weight conversion: OIHW fp32 -> bf16 [t][cb][koct][f][j] ----
__global__ void conv_wprep(const float* __restrict__ w, short* __restrict__ wbf) {
    int i = blockIdx.x * 256 + threadIdx.x;    // grid sized to exactly 36864
    int j = i & 7;
    int f = (i >> 3) & 63;
    int koct = (i >> 9) & 3;
    int cb = (i >> 11) & 1;
    int t = i >> 12;
    int c = cb * 32 + koct * 8 + j;
    int ky = t / 3, kx = t - ky * 3;
    wbf[i] = (short)f2bf(w[((f * CIN + c) * 3 + ky) * 3 + kx]);
}

template<int MT>
__device__ __forceinline__ void main_loop(const short* lds, const short* __restrict__ wbf,
                                          f32x4 (&acc)[4][2], bf16x8 (&br)[2][2][2],
                                          int r, int nh, int lm, int q)
{
#pragma unroll
    for (int t = 0; t < 9; ++t) {
        const int buf = t & 1;
        if (t < 8) {
#pragma unroll
            for (int ntl = 0; ntl < 2; ++ntl) {
                const int f = (nh * 2 + ntl) * 16 + lm;
                br[1 - buf][ntl][0] = *(const bf16x8*)(wbf + ((t + 1) * 8 + q) * 512 + f * 8);
                br[1 - buf][ntl][1] = *(const bf16x8*)(wbf + ((t + 1) * 8 + 4 + q) * 512 + f * 8);
            }
        }
        const int ky = t / 3, kx = t - ky * 3;
#pragma unroll
        for (int mt = 0; mt < MT; ++mt) {
            const int wcol = mt * 16 + lm + kx;
            const bf16x8 a0 = *(const bf16x8*)&lds[ladr(r + ky, q, wcol)];
            const bf16x8 a1 = *(const bf16x8*)&lds[ladr(r + ky, q + 4, wcol)];
#pragma unroll
            for (int ntl = 0; ntl < 2; ++ntl)
                acc[mt][ntl] = __builtin_amdgcn_mfma_f32_16x16x32_bf16(a0, br[buf][ntl][0], acc[mt][ntl], 0, 0, 0);
#pragma unroll
            for (int ntl = 0; ntl < 2; ++ntl)
                acc[mt][ntl] = __builtin_amdgcn_mfma_f32_16x16x32_bf16(a1, br[buf][ntl][1], acc[mt][ntl], 0, 0, 0);
        }
    }
}

__global__ __launch_bounds__(256, 4)
void conv3x3_mfma(const float* __restrict__ x, const short* __restrict__ wbf,
                  const float* __restrict__ bias, float* __restrict__ out)
{
    __shared__ __align__(16) short lds[LDS_SHORTS];
    const int tid = threadIdx.x;
    const int n = blockIdx.x;
    const int h0 = blockIdx.y * ROWS;
    const int ws = blockIdx.z;          // 0: out cols 0..63 (4 mt); 1: cols 64..111 (3 mt)
    const int MTN = ws ? 3 : 4;
    const int c0 = ws * 64;

    const int wave = tid >> 6;
    const int r  = wave >> 1;          // output row within block (0..1)
    const int nh = wave & 1;           // cout half (0..1)
    const int lane = tid & 63;
    const int lm = lane & 15;          // A: pixel m ; D: cout col
    const int q  = lane >> 4;          // k-octet index 0..3

    // ---- zero the padding column (wcol 0 for left block, wcol 49 for right) ----
    if (tid < 32) {
        const int dy = tid >> 3, oct = tid & 7;
        const int padw = ws ? 49 : 0;
        *(uint4*)&lds[ladr(dy, oct, padw)] = (uint4){0u, 0u, 0u, 0u};
    }
    // ---- zero out-of-bounds input planes (contiguous per dy) ----
    if (h0 == 0) {
        uint4* p = (uint4*)&lds[0];
        for (int i = tid; i < PLANE / 8; i += 256) p[i] = (uint4){0u, 0u, 0u, 0u};
    }
    if (h0 == HH - ROWS) {
        uint4* p = (uint4*)&lds[(DYS - 1) * PLANE];
        for (int i = tid; i < PLANE / 8; i += 256) p[i] = (uint4){0u, 0u, 0u, 0u};
    }
    // ---- interior staging: unit = (dy, ch-octet, w4) = 8ch x 4cols ----
    // left: 16 w4 units (gc 0..63); right: 12 w4 units (gc 64..111). float4-aligned.
    {
        const int W4N = ws ? 12 : 16;
        const int dy = tid >> 6, oct = (tid >> 3) & 7, w4lo = tid & 7;
        const int gh = h0 + dy - 1;
        if ((unsigned)gh < (unsigned)HH) {
            for (int w4 = w4lo; w4 < W4N; w4 += 8) {
                const float* px = x + (((n * CIN + oct * 8) * HH + gh) * WW + c0 + w4 * 4);
                float v[8][4];
#pragma unroll
                for (int k = 0; k < 8; ++k) {
                    const float4 t = *(const float4*)(px + k * HH * WW);
                    v[k][0] = t.x; v[k][1] = t.y; v[k][2] = t.z; v[k][3] = t.w;
                }
#pragma unroll
                for (int dw = 0; dw < 4; ++dw) {
                    uint4 pk;
                    pk.x = pk2bf(v[0][dw], v[1][dw]);
                    pk.y = pk2bf(v[2][dw], v[3][dw]);
                    pk.z = pk2bf(v[4][dw], v[5][dw]);
                    pk.w = pk2bf(v[6][dw], v[7][dw]);
                    *(uint4*)&lds[ladr(dy, oct, 1 + w4 * 4 + dw)] = pk;
                }
            }
        }
    }
    // ---- halo column: left block wcol 65 = gc 64; right block wcol 0 = gc 63 ----
    {
        const int dy = tid >> 6, c = tid & 63;
        const int gh = h0 + dy - 1;
        const int gce = ws ? 63 : 64;
        const int wedge = ws ? 0 : 65;
        if ((unsigned)gh < (unsigned)HH) {
            const float vv = x[((n * CIN + c) * HH + gh) * WW + gce];
            lds[ladr(dy, c >> 3, wedge) + (c & 7)] = (short)f2bf(vv);
        }
    }

    // ---- prefetch tap 0 B-fragments while staging drains ----
    bf16x8 br[2][2][2];                // [buf][ntl][cb]
#pragma unroll
    for (int ntl = 0; ntl < 2; ++ntl) {
        const int f = (nh * 2 + ntl) * 16 + lm;
        br[0][ntl][0] = *(const bf16x8*)(wbf + (q) * 512 + f * 8);
        br[0][ntl][1] = *(const bf16x8*)(wbf + (4 + q) * 512 + f * 8);
    }

    __syncthreads();

    f32x4 acc[4][2];
#pragma unroll
    for (int mt = 0; mt < 4; ++mt)
#pragma unroll
        for (int ntl = 0; ntl < 2; ++ntl) acc[mt][ntl] = (f32x4){0.f, 0.f, 0.f, 0.f};

    if (MTN == 4) main_loop<4>(lds, wbf, acc, br, r, nh, lm, q);
    else          main_loop<3>(lds, wbf, acc, br, r, nh, lm, q);

    // ---- epilogue: bias in-register, direct float4 stores (64B/cout contiguous) ----
    const int f0 = nh * 32 + lm;
    const float b0 = bias[f0];
    const float b1 = bias[f0 + 16];
    const int hrow = h0 + r;
#pragma unroll
    for (int mt = 0; mt < 4; ++mt) {
        if (mt < MTN) {
#pragma unroll
            for (int ntl = 0; ntl < 2; ++ntl) {
                const f32x4 v = acc[mt][ntl];
                const float bb = ntl ? b1 : b0;
                float4 s;
                s.x = v[0] + bb; s.y = v[1] + bb; s.z = v[2] + bb; s.w = v[3] + bb;
                const int f = f0 + ntl * 16;
                *(float4*)(out + ((n * COUT + f) * HH + hrow) * WW + c0 + mt * 16 + q * 4) = s;
            }
        }
    }
}

extern "C" void kernel_launch(void* const* d_in, const int* in_sizes, int n_in,
                              void* d_out, int out_size, void* d_ws, size_t ws_size,
                              hipStream_t stream) {
    const float* x = (const float*)d_in[0];
    const float* w = (const float*)d_in[1];
    const float* b = (const float*)d_in[2];
    float* out = (float*)d_out;
    short* wbf = (short*)d_ws;   // 36864 shorts = 73728 B

    conv_wprep<<<144, 256, 0, stream>>>(w, wbf);   // 144*256 == 36864 exactly
    // grid: x=n keeps each image's blocks on one XCD (id%8==n%8); y,z share the
    // same XCD for a given n so halo-row re-reads hit the same L2.
    dim3 grid(16, HH / ROWS, 2);
    conv3x3_mfma<<<grid, 256, 0, stream>>>(x, wbf, b, out);
}

// Round 3
// 124.122 us; speedup vs baseline: 1.0077x; 1.0077x over previous
//
#include <hip/hip_runtime.h>

// Conv2d 3x3 s1 p1, N=16 C=64 H=W=112 F=64, fp32 in/out, bf16 MFMA implicit GEMM.
// R7b (resubmit; R2 bench was an infra failure, no counters produced).
// Persistent h-strip blocks (grid 256 = 16n x 2ws x 8strips, 1 block/CU).
// Each block walks 7 2-row tiles down a 14-row strip; LDS is a ring of 8 row-
// planes (row&7), so consecutive tiles reuse 2 of 4 staged input rows (-43%
// staging). Async-stage split: next-tile global loads issue BEFORE the 9-tap
// MFMA loop, convert+ds_write land AFTER it (latency hidden under ~2000 cyc of
// MFMA). Weights for all 9 taps live in 144 VGPRs for the whole strip -> zero
// global loads in the steady-state tap loop. One barrier per tile.
// LDS plane layout [oct][wcol][8ch] (16B/wcol): A-reads bank-balanced (8 lanes
// per 4-bank group).

typedef __attribute__((ext_vector_type(8))) short bf16x8;
typedef __attribute__((ext_vector_type(4))) float f32x4;

#define CIN 64
#define COUT 64
#define HH 112
#define WW 112
#define ROWS 2                    // output rows per tile
#define TILES 7                   // tiles per strip
#define STRIPH (ROWS * TILES)     // 14 rows per strip
#define NPL 8                     // ring planes (power of 2)
#define WCMAX 66                  // staged wcols per plane (pad + 64 + halo)
#define PLANE (8 * WCMAX * 8)     // shorts per plane = 4224 (8448 B)
#define LDS_SHORTS (NPL * PLANE)  // 33792 shorts = 67584 B

__device__ __forceinline__ int ladr(int pl, int oct, int w) {
    // bf16 [plane][oct][wcol][8ch]; addr in shorts. Bank group of 16B unit:
    // (2*oct + wcol) & 7 -> balanced for A-reads (lm sweeps 16 wcols).
    return ((pl * 8 + oct) * WCMAX + w) * 8;
}

__device__ __forceinline__ unsigned short f2bf(float f) {
    unsigned u = __builtin_bit_cast(unsigned, f);
    u += 0x7FFFu + ((u >> 16) & 1u);   // round-to-nearest-even
    return (unsigned short)(u >> 16);
}

#if __has_builtin(__builtin_amdgcn_cvt_pk_bf16_f32)
__device__ __forceinline__ unsigned pk2bf(float a, float b) {
    typedef __attribute__((ext_vector_type(2))) __bf16 bf16x2;
    bf16x2 r = __builtin_amdgcn_cvt_pk_bf16_f32(a, b);
    return __builtin_bit_cast(unsigned, r);
}
#else
__device__ __forceinline__ unsigned pk2bf(float a, float b) {
    return (unsigned)f2bf(a) | ((unsigned)f2bf(b) << 16);
}
#endif

// ---- one-time weight conversion: OIHW fp32 -> bf16 [t][cb][koct][f][j] ----
__global__ void conv_wprep(const float* __restrict__ w, short* __restrict__ wbf) {
    int i = blockIdx.x * 256 + threadIdx.x;    // grid sized to exactly 36864
    int j = i & 7;
    int f = (i >> 3) & 63;
    int koct = (i >> 9) & 3;
    int cb = (i >> 11) & 1;
    int t = i >> 12;
    int c = cb * 32 + koct * 8 + j;
    int ky = t / 3, kx = t - ky * 3;
    wbf[i] = (short)f2bf(w[((f * CIN + c) * 3 + ky) * 3 + kx]);
}

struct StageRegs {
    float v[8][4];   // 8 channels x 4 cols staged in registers
    float hv;        // halo-column value
};

// Issue the global loads for a 2-row stage (unit: re=tid>>7, oct, w4) into regs.
__device__ __forceinline__ void stage_load(const float* __restrict__ x, int tid,
                                           int n, int c0, int W4N, int gce,
                                           int row0, StageRegs& sr)
{
    const int re  = tid >> 7;
    const int oct = (tid >> 4) & 7;
    const int w4  = tid & 15;
    const int row = row0 + re;
    sr.hv = 0.f;
#pragma unroll
    for (int k = 0; k < 8; ++k)
#pragma unroll
        for (int d = 0; d < 4; ++d) sr.v[k][d] = 0.f;
    if ((unsigned)row < (unsigned)HH && w4 < W4N) {
        const float* px = x + (((n * CIN + oct * 8) * HH + row) * WW + c0 + w4 * 4);
#pragma unroll
        for (int k = 0; k < 8; ++k) {
            const float4 t = *(const float4*)(px + k * HH * WW);
            sr.v[k][0] = t.x; sr.v[k][1] = t.y; sr.v[k][2] = t.z; sr.v[k][3] = t.w;
        }
    }
    if (tid < 128) {             // halo col: 2 rows x 64 ch
        const int hrow = row0 + (tid >> 6);
        const int c = tid & 63;
        if ((unsigned)hrow < (unsigned)HH)
            sr.hv = x[((n * CIN + c) * HH + hrow) * WW + gce];
    }
}

// Convert + write the staged regs into the ring planes (after the tap loop).
__device__ __forceinline__ void stage_write(short* lds, int tid, int W4N,
                                            int padw, int wedge, int row0,
                                            const StageRegs& sr)
{
    const int re  = tid >> 7;
    const int oct = (tid >> 4) & 7;
    const int w4  = tid & 15;
    const int row = row0 + re;
    const int pl  = row & (NPL - 1);
    if (w4 < W4N) {
#pragma unroll
        for (int dw = 0; dw < 4; ++dw) {
            uint4 pk;
            pk.x = pk2bf(sr.v[0][dw], sr.v[1][dw]);
            pk.y = pk2bf(sr.v[2][dw], sr.v[3][dw]);
            pk.z = pk2bf(sr.v[4][dw], sr.v[5][dw]);
            pk.w = pk2bf(sr.v[6][dw], sr.v[7][dw]);
            *(uint4*)&lds[ladr(pl, oct, 1 + w4 * 4 + dw)] = pk;
        }
    }
    if (tid < 128) {             // halo col
        const int hrow = row0 + (tid >> 6);
        const int c = tid & 63;
        const int hpl = hrow & (NPL - 1);
        lds[ladr(hpl, c >> 3, wedge) + (c & 7)] = (short)f2bf(sr.hv);
    }
    if (tid < 16) {              // pad col zero: 2 rows x 8 octs
        const int prow = row0 + (tid >> 3);
        const int ppl = prow & (NPL - 1);
        *(uint4*)&lds[ladr(ppl, tid & 7, padw)] = (uint4){0u, 0u, 0u, 0u};
    }
}

__global__ __launch_bounds__(256, 1)
void conv3x3_mfma(const float* __restrict__ x, const short* __restrict__ wbf,
                  const float* __restrict__ bias, float* __restrict__ out)
{
    __shared__ __align__(16) short lds[LDS_SHORTS];
    const int tid = threadIdx.x;
    const int n = blockIdx.x;
    const int ws = blockIdx.y;          // 0: out cols 0..63 (4 mt); 1: 64..111 (3 mt)
    const int strip = blockIdx.z;
    const int hb = strip * STRIPH;

    const int MTN  = ws ? 3 : 4;
    const int W4N  = ws ? 12 : 16;
    const int c0   = ws * 64;
    const int padw = ws ? 49 : 0;
    const int gce  = ws ? 63 : 64;
    const int wedge = ws ? 0 : 65;

    const int wave = tid >> 6;
    const int r  = wave >> 1;          // output row within tile (0..1)
    const int nh = wave & 1;           // cout half (0..1)
    const int lane = tid & 63;
    const int lm = lane & 15;          // A: pixel m ; D: cout col
    const int q  = lane >> 4;          // k-octet index 0..3

    StageRegs sr;

    // ---- prologue: stage rows hb-1 .. hb+2 into ring slots ----
    stage_load(x, tid, n, c0, W4N, gce, hb - 1, sr);
    stage_write(lds, tid, W4N, padw, wedge, hb - 1, sr);
    stage_load(x, tid, n, c0, W4N, gce, hb + 1, sr);
    stage_write(lds, tid, W4N, padw, wedge, hb + 1, sr);

    // ---- B preload: all 9 taps x 2 ntl x 2 cb = 36 frags (144 VGPR), strip-resident ----
    bf16x8 bw[9][2][2];
#pragma unroll
    for (int t = 0; t < 9; ++t)
#pragma unroll
        for (int ntl = 0; ntl < 2; ++ntl) {
            const int f = (nh * 2 + ntl) * 16 + lm;
            bw[t][ntl][0] = *(const bf16x8*)(wbf + (t * 8 + q) * 512 + f * 8);
            bw[t][ntl][1] = *(const bf16x8*)(wbf + (t * 8 + 4 + q) * 512 + f * 8);
        }

    const int f0 = nh * 32 + lm;
    const float b0 = bias[f0];
    const float b1 = bias[f0 + 16];

    __syncthreads();

    for (int t = 0; t < TILES; ++t) {
        const int h0 = hb + 2 * t;
        const bool do_stage = (t < TILES - 1);

        // issue next-tile loads early: latency hides under the tap loop
        if (do_stage) stage_load(x, tid, n, c0, W4N, gce, h0 + 3, sr);

        f32x4 acc[4][2];
#pragma unroll
        for (int mt = 0; mt < 4; ++mt)
#pragma unroll
            for (int ntl = 0; ntl < 2; ++ntl) acc[mt][ntl] = (f32x4){0.f, 0.f, 0.f, 0.f};

#pragma unroll
        for (int tap = 0; tap < 9; ++tap) {
            const int ky = tap / 3, kx = tap - ky * 3;
            const int pl = (h0 - 1 + r + ky) & (NPL - 1);
#pragma unroll
            for (int mt = 0; mt < 4; ++mt) {
                if (mt < MTN) {
                    const int wcol = mt * 16 + lm + kx;
                    const bf16x8 a0 = *(const bf16x8*)&lds[ladr(pl, q, wcol)];
                    const bf16x8 a1 = *(const bf16x8*)&lds[ladr(pl, q + 4, wcol)];
                    acc[mt][0] = __builtin_amdgcn_mfma_f32_16x16x32_bf16(a0, bw[tap][0][0], acc[mt][0], 0, 0, 0);
                    acc[mt][1] = __builtin_amdgcn_mfma_f32_16x16x32_bf16(a0, bw[tap][1][0], acc[mt][1], 0, 0, 0);
                    acc[mt][0] = __builtin_amdgcn_mfma_f32_16x16x32_bf16(a1, bw[tap][0][1], acc[mt][0], 0, 0, 0);
                    acc[mt][1] = __builtin_amdgcn_mfma_f32_16x16x32_bf16(a1, bw[tap][1][1], acc[mt][1], 0, 0, 0);
                }
            }
        }

        // convert + LDS-write the prefetched rows (targets slots no tap reads)
        if (do_stage) stage_write(lds, tid, W4N, padw, wedge, h0 + 3, sr);

        // ---- epilogue: bias in-register, direct float4 stores ----
        const int hrow = h0 + r;
#pragma unroll
        for (int mt = 0; mt < 4; ++mt) {
            if (mt < MTN) {
#pragma unroll
                for (int ntl = 0; ntl < 2; ++ntl) {
                    const f32x4 v = acc[mt][ntl];
                    const float bb = ntl ? b1 : b0;
                    float4 s;
                    s.x = v[0] + bb; s.y = v[1] + bb; s.z = v[2] + bb; s.w = v[3] + bb;
                    *(float4*)(out + ((n * COUT + f0 + ntl * 16) * HH + hrow) * WW
                               + c0 + mt * 16 + q * 4) = s;
                }
            }
        }

        __syncthreads();   // writes(t+1 planes) visible before taps(t+1)
    }
}

extern "C" void kernel_launch(void* const* d_in, const int* in_sizes, int n_in,
                              void* d_out, int out_size, void* d_ws, size_t ws_size,
                              hipStream_t stream) {
    const float* x = (const float*)d_in[0];
    const float* w = (const float*)d_in[1];
    const float* b = (const float*)d_in[2];
    float* out = (float*)d_out;
    short* wbf = (short*)d_ws;   // 36864 shorts = 73728 B

    conv_wprep<<<144, 256, 0, stream>>>(w, wbf);   // 144*256 == 36864 exactly
    // grid: 256 blocks = 1/CU; linear id % 8 == n % 8 keeps each image's strip
    // blocks on one XCD so row re-reads stay in that XCD's L2.
    dim3 grid(16, 2, 8);
    conv3x3_mfma<<<grid, 256, 0, stream>>>(x, wbf, b, out);
}

// Round 4
// 115.711 us; speedup vs baseline: 1.0810x; 1.0727x over previous
//
#include <hip/hip_runtime.h>

// Conv2d 3x3 s1 p1, N=16 C=64 H=W=112 F=64, fp32 in/out, bf16 MFMA implicit GEMM.
// R8: R7's persistent-strip pipeline, fixed for latency coverage.
//  - 512-thread blocks (8 waves = 2/SIMD): tap-loop ds_read latency covered by
//    TLP (R7's 1 wave/SIMD exposed it -> 1.42 TB/s HBM starvation).
//  - Waves = (r, nh, mh): row x cout-half x mt-half; 2 m-tiles per wave per tap.
//  - Persistent 14-row strips, 7 tiles of 2 rows, LDS ring of 8 row-planes
//    (row&7): 1.14x fetch redundancy; stage loads issue BEFORE the tap loop,
//    convert+ds_write after (async-stage split).
//  - Weights strip-resident: bw[9][2][2] = 144 VGPR, zero loads in tap loop.
//  - Plane pitch 67 units (was 66): 16B-unit bank residue = (3*oct+wcol)&7
//    sweeps all 8 residues for BOTH staging writes and A-reads -> conflicts ~0.

typedef __attribute__((ext_vector_type(8))) short bf16x8;
typedef __attribute__((ext_vector_type(4))) float f32x4;

#define CIN 64
#define COUT 64
#define HH 112
#define WW 112
#define ROWS 2                    // output rows per tile
#define TILES 7                   // tiles per strip
#define STRIPH (ROWS * TILES)     // 14 rows per strip
#define NPL 8                     // ring planes (power of 2)
#define WPITCH 67                 // wcol pitch (66 used + 1 pad unit): bank fix
#define PLANE_SHORTS (8 * WPITCH * 8)    // 4288 shorts = 8576 B per plane
#define LDS_SHORTS (NPL * PLANE_SHORTS)  // 34304 shorts = 68608 B

__device__ __forceinline__ int ladr(int pl, int oct, int w) {
    // bf16 [plane][oct][wcol][8ch]; addr in shorts. 16B-unit index =
    // (pl*8+oct)*67 + w; residue mod 8 = (3*oct + w) & 7 (67 = 8*8+3).
    return ((pl * 8 + oct) * WPITCH + w) * 8;
}

__device__ __forceinline__ unsigned short f2bf(float f) {
    unsigned u = __builtin_bit_cast(unsigned, f);
    u += 0x7FFFu + ((u >> 16) & 1u);   // round-to-nearest-even
    return (unsigned short)(u >> 16);
}

#if __has_builtin(__builtin_amdgcn_cvt_pk_bf16_f32)
__device__ __forceinline__ unsigned pk2bf(float a, float b) {
    typedef __attribute__((ext_vector_type(2))) __bf16 bf16x2;
    bf16x2 r = __builtin_amdgcn_cvt_pk_bf16_f32(a, b);
    return __builtin_bit_cast(unsigned, r);
}
#else
__device__ __forceinline__ unsigned pk2bf(float a, float b) {
    return (unsigned)f2bf(a) | ((unsigned)f2bf(b) << 16);
}
#endif

// ---- one-time weight conversion: OIHW fp32 -> bf16 [t][cb][koct][f][j] ----
__global__ void conv_wprep(const float* __restrict__ w, short* __restrict__ wbf) {
    int i = blockIdx.x * 256 + threadIdx.x;    // grid sized to exactly 36864
    int j = i & 7;
    int f = (i >> 3) & 63;
    int koct = (i >> 9) & 3;
    int cb = (i >> 11) & 1;
    int t = i >> 12;
    int c = cb * 32 + koct * 8 + j;
    int ky = t / 3, kx = t - ky * 3;
    wbf[i] = (short)f2bf(w[((f * CIN + c) * 3 + ky) * 3 + kx]);
}

struct StageRegs {
    float4 v[8];   // interior unit: 8 channels x 4 cols (tid < 256)
    float hv;      // halo-column value (tid in [256,384))
};

// Issue global loads for a 2-row stage into regs. Wave-uniform branches:
// waves 0-3 = interior units (re,oct,w4); waves 4-5 = halo column.
__device__ __forceinline__ void stage_load(const float* __restrict__ x, int tid,
                                           int n, int c0, int W4N, int gce,
                                           int row0, StageRegs& sr)
{
    if (tid < 256) {
        const int re = tid >> 7, oct = (tid >> 4) & 7, w4 = tid & 15;
        const int row = row0 + re;
#pragma unroll
        for (int k = 0; k < 8; ++k) sr.v[k] = (float4){0.f, 0.f, 0.f, 0.f};
        if ((unsigned)row < (unsigned)HH && w4 < W4N) {
            const float* px = x + (((n * CIN + oct * 8) * HH + row) * WW + c0 + w4 * 4);
#pragma unroll
            for (int k = 0; k < 8; ++k) sr.v[k] = *(const float4*)(px + k * HH * WW);
        }
    } else if (tid < 384) {
        const int i = tid - 256;
        const int row = row0 + (i >> 6);
        sr.hv = 0.f;
        if ((unsigned)row < (unsigned)HH)
            sr.hv = x[((n * CIN + (i & 63)) * HH + row) * WW + gce];
    }
}

// Convert + write staged regs into ring planes (rows out of [0,HH) write zeros,
// which is exactly the padding the taps expect).
__device__ __forceinline__ void stage_write(short* lds, int tid, int W4N,
                                            int padw, int wedge, int row0,
                                            const StageRegs& sr)
{
    if (tid < 256) {
        const int re = tid >> 7, oct = (tid >> 4) & 7, w4 = tid & 15;
        const int pl = (row0 + re) & (NPL - 1);
        if (w4 < W4N) {
            const float* fv = (const float*)&sr.v[0];
#pragma unroll
            for (int dw = 0; dw < 4; ++dw) {
                uint4 pk;
                pk.x = pk2bf(fv[0 * 4 + dw], fv[1 * 4 + dw]);
                pk.y = pk2bf(fv[2 * 4 + dw], fv[3 * 4 + dw]);
                pk.z = pk2bf(fv[4 * 4 + dw], fv[5 * 4 + dw]);
                pk.w = pk2bf(fv[6 * 4 + dw], fv[7 * 4 + dw]);
                *(uint4*)&lds[ladr(pl, oct, 1 + w4 * 4 + dw)] = pk;
            }
        }
    } else if (tid < 384) {
        const int i = tid - 256;
        const int row = row0 + (i >> 6);
        const int pl = row & (NPL - 1);
        const int c = i & 63;
        lds[ladr(pl, c >> 3, wedge) + (c & 7)] = (short)f2bf(sr.hv);
    } else if (tid < 400) {
        const int i = tid - 384;
        const int pl = (row0 + (i >> 3)) & (NPL - 1);
        *(uint4*)&lds[ladr(pl, i & 7, padw)] = (uint4){0u, 0u, 0u, 0u};
    }
}

__global__ __launch_bounds__(512, 2)
void conv3x3_mfma(const float* __restrict__ x, const short* __restrict__ wbf,
                  const float* __restrict__ bias, float* __restrict__ out)
{
    __shared__ __align__(16) short lds[LDS_SHORTS];
    const int tid = threadIdx.x;
    const int n = blockIdx.x;
    const int ws = blockIdx.y;          // 0: out cols 0..63; 1: cols 64..111
    const int hb = blockIdx.z * STRIPH;

    const int MTN   = ws ? 3 : 4;
    const int W4N   = ws ? 12 : 16;
    const int c0    = ws * 64;
    const int padw  = ws ? 49 : 0;
    const int gce   = ws ? 63 : 64;
    const int wedge = ws ? 0 : 65;

    const int wave = tid >> 6;         // 0..7
    const int r  = wave >> 2;          // output row within tile (0..1)
    const int nh = (wave >> 1) & 1;    // cout half
    const int mh = wave & 1;           // mt half
    const int lane = tid & 63;
    const int lm = lane & 15;          // A: pixel m ; D: cout col
    const int q  = lane >> 4;          // k-octet index 0..3

    StageRegs sr;

    // ---- prologue: stage rows hb-1 .. hb+2 into ring slots ----
    stage_load(x, tid, n, c0, W4N, gce, hb - 1, sr);
    stage_write(lds, tid, W4N, padw, wedge, hb - 1, sr);
    stage_load(x, tid, n, c0, W4N, gce, hb + 1, sr);
    stage_write(lds, tid, W4N, padw, wedge, hb + 1, sr);

    // ---- B preload: 9 taps x 2 ntl x 2 cb = 36 frags (144 VGPR), strip-resident ----
    bf16x8 bw[9][2][2];
#pragma unroll
    for (int t = 0; t < 9; ++t)
#pragma unroll
        for (int ntl = 0; ntl < 2; ++ntl) {
            const int f = nh * 32 + ntl * 16 + lm;
            bw[t][ntl][0] = *(const bf16x8*)(wbf + (t * 8 + q) * 512 + f * 8);
            bw[t][ntl][1] = *(const bf16x8*)(wbf + (t * 8 + 4 + q) * 512 + f * 8);
        }

    const int f0 = nh * 32 + lm;
    const float b0 = bias[f0];
    const float b1 = bias[f0 + 16];

    __syncthreads();

    for (int t = 0; t < TILES; ++t) {
        const int h0 = hb + 2 * t;
        const bool do_stage = (t < TILES - 1);

        // issue next-tile loads early: latency hides under the tap loop
        if (do_stage) stage_load(x, tid, n, c0, W4N, gce, h0 + 3, sr);

        f32x4 acc[2][2];
#pragma unroll
        for (int j = 0; j < 2; ++j)
#pragma unroll
            for (int ntl = 0; ntl < 2; ++ntl) acc[j][ntl] = (f32x4){0.f, 0.f, 0.f, 0.f};

#pragma unroll
        for (int tap = 0; tap < 9; ++tap) {
            const int ky = tap / 3, kx = tap - ky * 3;
            const int pl = (h0 - 1 + r + ky) & (NPL - 1);
#pragma unroll
            for (int j = 0; j < 2; ++j) {
                const int mt = mh * 2 + j;
                if (mt < MTN) {
                    const int wcol = mt * 16 + lm + kx;
                    const bf16x8 a0 = *(const bf16x8*)&lds[ladr(pl, q, wcol)];
                    const bf16x8 a1 = *(const bf16x8*)&lds[ladr(pl, q + 4, wcol)];
                    acc[j][0] = __builtin_amdgcn_mfma_f32_16x16x32_bf16(a0, bw[tap][0][0], acc[j][0], 0, 0, 0);
                    acc[j][1] = __builtin_amdgcn_mfma_f32_16x16x32_bf16(a0, bw[tap][1][0], acc[j][1], 0, 0, 0);
                    acc[j][0] = __builtin_amdgcn_mfma_f32_16x16x32_bf16(a1, bw[tap][0][1], acc[j][0], 0, 0, 0);
                    acc[j][1] = __builtin_amdgcn_mfma_f32_16x16x32_bf16(a1, bw[tap][1][1], acc[j][1], 0, 0, 0);
                }
            }
        }

        // convert + LDS-write prefetched rows (planes h0+3,h0+4: no tap reads them)
        if (do_stage) stage_write(lds, tid, W4N, padw, wedge, h0 + 3, sr);

        // ---- epilogue: bias in-register, direct float4 stores ----
        const int hrow = h0 + r;
#pragma unroll
        for (int j = 0; j < 2; ++j) {
            const int mt = mh * 2 + j;
            if (mt < MTN) {
#pragma unroll
                for (int ntl = 0; ntl < 2; ++ntl) {
                    const f32x4 v = acc[j][ntl];
                    const float bb = ntl ? b1 : b0;
                    float4 s;
                    s.x = v[0] + bb; s.y = v[1] + bb; s.z = v[2] + bb; s.w = v[3] + bb;
                    *(float4*)(out + ((n * COUT + f0 + ntl * 16) * HH + hrow) * WW
                               + c0 + mt * 16 + q * 4) = s;
                }
            }
        }

        __syncthreads();   // writes(t+1 planes) visible before taps(t+1)
    }
}

extern "C" void kernel_launch(void* const* d_in, const int* in_sizes, int n_in,
                              void* d_out, int out_size, void* d_ws, size_t ws_size,
                              hipStream_t stream) {
    const float* x = (const float*)d_in[0];
    const float* w = (const float*)d_in[1];
    const float* b = (const float*)d_in[2];
    float* out = (float*)d_out;
    short* wbf = (short*)d_ws;   // 36864 shorts = 73728 B

    conv_wprep<<<144, 256, 0, stream>>>(w, wbf);   // 144*256 == 36864 exactly
    // grid: 256 blocks = 1/CU, 8 waves each (2/SIMD). linear id % 8 == n % 8
    // keeps each image's strip blocks on one XCD for halo-row L2 reuse.
    dim3 grid(16, 2, 8);
    conv3x3_mfma<<<grid, 512, 0, stream>>>(x, wbf, b, out);
}